// Round 7
// baseline (199.542 us; speedup 1.0000x reference)
//
#include <hip/hip_runtime.h>
#include <hip/hip_bf16.h>

#define NV 16384
#define NT 256
#define NTILES 512                  // 32-point MFMA tiles per mesh
#define RT_CHUNK 64                 // ref tiles per nn block (chunk)
#define NCHUNK (NTILES / RT_CHUNK)  // 8 chunks per direction
#define STG 32                      // tiles staged in LDS per round (32 KB)
#define QT_PER_BLOCK 8              // 4 waves x 2 qtiles
#define NN_BX (NTILES / QT_PER_BLOCK)  // 64
#define RES_QPW 4                   // queries per wave (resolve)
#define RES_QPB (4 * RES_QPW)       // 16 per block
#define RES_BLOCKS (NV / RES_QPB)   // 1024 per direction
#define NPART (2 * RES_BLOCKS)      // 2048 partials

typedef __attribute__((ext_vector_type(8))) short bf16x8;
typedef __attribute__((ext_vector_type(16))) float f32x16;

__device__ __forceinline__ short bf16bits(float f) {
    __hip_bfloat16 h = __float2bfloat16(f);
    return *reinterpret_cast<short*>(&h);
}
__device__ __forceinline__ float bf16tof(short s) {
    __hip_bfloat16 h = *reinterpret_cast<__hip_bfloat16*>(&s);
    return __bfloat162float(h);
}
__device__ __forceinline__ unsigned sortable(float f) {
    unsigned u = __float_as_uint(f);
    return (u & 0x80000000u) ? ~u : (u | 0x80000000u);
}
__device__ __forceinline__ float min3f(float a, float b, float c) {
    float r;
    asm("v_min3_f32 %0, %1, %2, %3" : "=v"(r) : "v"(a), "v"(b), "v"(c));
    return r;
}
// min over the 16 f32 of one MFMA accumulator (in-lane), 8 ops, depth 3
__device__ __forceinline__ float tree16(const f32x16& c) {
    float t0 = min3f(c[0], c[1], c[2]);
    float t1 = min3f(c[3], c[4], c[5]);
    float t2 = min3f(c[6], c[7], c[8]);
    float t3 = min3f(c[9], c[10], c[11]);
    float t4 = min3f(c[12], c[13], c[14]);
    float s0 = min3f(t0, t1, c[15]);
    float s1 = min3f(t2, t3, t4);
    return fminf(s0, s1);
}

// Fragment packing (K=11 of 16). Metric m(ref,query) = 0.5*||r||^2 - q.r:
//   A(ref) k:   [rh.x rh.y rh.z | rl.x rl.y rl.z | rh.x rh.y || rh.z nh nl | 0..]
//   B(query) k: [-qh.x -qh.y -qh.z | -qh.x -qh.y -qh.z | -ql.x -ql.y || -ql.z 1 1 | 0..]
// vh = bf16(v), vl = bf16(v - f32(vh)), n = 0.5||r||^2 split nh+nl.
// A and B use the same (half,elem)->k mapping so any permutation cancels.
__device__ __forceinline__ bf16x8 make_a(float x, float y, float z, int half) {
    short hx = bf16bits(x), hy = bf16bits(y), hz = bf16bits(z);
    short lx = bf16bits(x - bf16tof(hx));
    short ly = bf16bits(y - bf16tof(hy));
    short lz = bf16bits(z - bf16tof(hz));
    float n  = 0.5f * fmaf(z, z, fmaf(y, y, x * x));
    short nh = bf16bits(n);
    short nl = bf16bits(n - bf16tof(nh));
    bf16x8 v;
    v[0] = half ? hz : hx;  v[1] = half ? nh : hy;
    v[2] = half ? nl : hz;  v[3] = half ? (short)0 : lx;
    v[4] = half ? (short)0 : ly;  v[5] = half ? (short)0 : lz;
    v[6] = half ? (short)0 : hx;  v[7] = half ? (short)0 : hy;
    return v;
}
__device__ __forceinline__ bf16x8 make_b(float x, float y, float z, int half) {
    short hx = bf16bits(x), hy = bf16bits(y), hz = bf16bits(z);
    short nhx = bf16bits(-x), nhy = bf16bits(-y), nhz = bf16bits(-z);
    short nlx = bf16bits(bf16tof(hx) - x);
    short nly = bf16bits(bf16tof(hy) - y);
    short nlz = bf16bits(bf16tof(hz) - z);
    const short one = 0x3F80;
    bf16x8 v;
    v[0] = half ? nlz : nhx;  v[1] = half ? one : nhy;
    v[2] = half ? one : nhz;  v[3] = half ? (short)0 : nhx;
    v[4] = half ? (short)0 : nhy;  v[5] = half ? (short)0 : nhz;
    v[6] = half ? (short)0 : nlx;  v[7] = half ? (short)0 : nly;
    return v;
}

// Pack all A (ref-side) fragments once (1 MB, L2-resident); zero done-counter.
__global__ __launch_bounds__(NT) void prep_kernel(
    const float* __restrict__ pred_v, const float* __restrict__ trg_v,
    short* __restrict__ Apack, unsigned* __restrict__ donecnt)
{
    int gid = blockIdx.x * NT + threadIdx.x;  // 0..65535
    if (gid == 0) donecnt[0] = 0;
    int d   = gid >> 15;                      // direction
    int rem = gid & 32767;
    int t   = rem >> 6;
    int l   = rem & 63;
    const float* rpts = d ? trg_v : pred_v;   // refs for dir d
    int p = t * 32 + (l & 31);
    bf16x8 v = make_a(rpts[3 * p + 0], rpts[3 * p + 1], rpts[3 * p + 2], l >> 5);
    *(bf16x8*)(Apack + ((size_t)gid) * 8) = v;
}

// Pass 1: MFMA all-pairs min. Block: 4 waves x 2 qtiles, one 64-rtile chunk,
// one direction. One a-tile per inner iteration; each MFMA's accumulator is
// reduced by its min3 tree immediately (<=2 live f32x16 -> no VGPR bound, no
// spill). pid tracked at single-rtile granularity (32-point resolve window).
__global__ __launch_bounds__(NT) void nn_mfma_kernel(
    const float* __restrict__ pred_v, const float* __restrict__ trg_v,
    const short* __restrict__ Apack, unsigned long long* __restrict__ results)
{
    __shared__ short lds[STG * 512];   // 32 KB
    const int tid = threadIdx.x, lane = tid & 63, w = tid >> 6;
    const int dir = blockIdx.z;
    const float* qpts = dir ? pred_v : trg_v;
    const int qt0 = blockIdx.x * QT_PER_BLOCK + w * 2;
    const int rtb = blockIdx.y * RT_CHUNK;
    const int half = lane >> 5;
    const size_t dbase = (size_t)dir * NTILES * 512;

    const int qp0 = qt0 * 32 + (lane & 31);
    bf16x8 b0 = make_b(qpts[3 * qp0 + 0], qpts[3 * qp0 + 1], qpts[3 * qp0 + 2], half);
    bf16x8 b1 = make_b(qpts[3 * (qp0 + 32) + 0], qpts[3 * (qp0 + 32) + 1],
                       qpts[3 * (qp0 + 32) + 2], half);

    float dmin0 = 1e30f, dmin1 = 1e30f;
    int bp0 = 0, bp1 = 0;
    const f32x16 zc = {};

    for (int g = 0; g < RT_CHUNK / STG; g++) {
        __syncthreads();
        const bf16x8* src = (const bf16x8*)(Apack + dbase + (size_t)(rtb + g * STG) * 512);
#pragma unroll
        for (int s = 0; s < (STG * 64) / NT; s++) {
            int slot = s * NT + tid;
            *(bf16x8*)(&lds[slot * 8]) = src[slot];
        }
        __syncthreads();
#pragma unroll 2
        for (int t = 0; t < STG; t++) {
            bf16x8 a = *(const bf16x8*)(&lds[t * 512 + lane * 8]);
            int tile = rtb + g * STG + t;
            f32x16 c0 = __builtin_amdgcn_mfma_f32_32x32x16_bf16(a, b0, zc, 0, 0, 0);
            float m0 = tree16(c0);
            bool lt0 = m0 < dmin0;
            dmin0 = lt0 ? m0 : dmin0;
            bp0 = lt0 ? tile : bp0;
            f32x16 c1 = __builtin_amdgcn_mfma_f32_32x32x16_bf16(a, b1, zc, 0, 0, 0);
            float m1 = tree16(c1);
            bool lt1 = m1 < dmin1;
            dmin1 = lt1 ? m1 : dmin1;
            bp1 = lt1 ? tile : bp1;
        }
    }

    unsigned long long k0 = ((unsigned long long)sortable(dmin0) << 32) | (unsigned)bp0;
    unsigned long long k1 = ((unsigned long long)sortable(dmin1) << 32) | (unsigned)bp1;
    unsigned long long o0 = __shfl_xor(k0, 32); k0 = (o0 < k0) ? o0 : k0;
    unsigned long long o1 = __shfl_xor(k1, 32); k1 = (o1 < k1) ? o1 : k1;
    if (lane < 32) {
        size_t base = ((size_t)dir * NCHUNK + blockIdx.y) * NV;
        results[base + qt0 * 32 + lane] = k0;
        results[base + (qt0 + 1) * 32 + lane] = k1;
    }
}

// Pass 2 + loss + final (last-block pattern). Per query: min over 8 chunk
// keys (lowest tile wins ties), exact fp32 rescan of the winning 32-point
// tile (lanes 32-63 duplicate lanes 0-31; packed-u64 lane-min -> first-
// occurrence argmin), lane 0 accumulates MSE. Deterministic block reduce to
// partials; the last block to finish sums partials in fixed order.
__global__ __launch_bounds__(NT) void resolve_loss_kernel(
    const float* __restrict__ pred_v, const float* __restrict__ trg_v,
    const float* __restrict__ pred_e, const float* __restrict__ trg_e,
    const unsigned long long* __restrict__ results, float* __restrict__ partials,
    unsigned* __restrict__ donecnt, float* __restrict__ out)
{
    const int dir = blockIdx.y;
    const float* qpts = dir ? pred_v : trg_v;
    const float* rpts = dir ? trg_v : pred_v;
    const float* qe_b = dir ? pred_e : trg_e;
    const float* re_b = dir ? trg_e : pred_e;

    const int tid = threadIdx.x, lane = tid & 63, wv = tid >> 6;
    float acc = 0.0f;

    for (int qq = 0; qq < RES_QPW; qq++) {
        const int q = blockIdx.x * RES_QPB + wv * RES_QPW + qq;

        unsigned long long key = 0xFFFFFFFFFFFFFFFFULL;
        if (lane < NCHUNK)
            key = results[((size_t)dir * NCHUNK + lane) * NV + q];
        unsigned long long o;
        o = __shfl_xor(key, 4); key = (o < key) ? o : key;
        o = __shfl_xor(key, 2); key = (o < key) ? o : key;
        o = __shfl_xor(key, 1); key = (o < key) ? o : key;
        key = __shfl(key, 0);
        const int tile = (int)(unsigned)(key & 0xFFFFFFFFULL);
        const int i = tile * 32 + (lane & 31);   // lanes 32-63 duplicate

        float nqx = -qpts[3 * q + 0], nqy = -qpts[3 * q + 1], nqz = -qpts[3 * q + 2];
        float x = rpts[3 * i + 0], y = rpts[3 * i + 1], z = rpts[3 * i + 2];
        float rw = 0.5f * fmaf(z, z, fmaf(y, y, x * x));
        float s = fmaf(nqx, x, rw);
        s = fmaf(nqy, y, s);
        s = fmaf(nqz, z, s);

        unsigned long long kk = ((unsigned long long)sortable(s) << 32) | (unsigned)i;
#pragma unroll
        for (int off = 32; off > 0; off >>= 1) {
            unsigned long long t = __shfl_xor(kk, off);
            kk = (t < kk) ? t : kk;
        }
        if (lane == 0) {
            int j = (int)(unsigned)(kk & 0xFFFFFFFFULL);
            float dx = qe_b[3 * q + 0] - re_b[3 * j + 0];
            float dy = qe_b[3 * q + 1] - re_b[3 * j + 1];
            float dz = qe_b[3 * q + 2] - re_b[3 * j + 2];
            acc += fmaf(dx, dx, fmaf(dy, dy, dz * dz));
        }
    }

    __shared__ float wsum[4];
    if (lane == 0) wsum[wv] = acc;
    __syncthreads();
    if (tid == 0)
        partials[dir * RES_BLOCKS + blockIdx.x] =
            (wsum[0] + wsum[1]) + (wsum[2] + wsum[3]);

    // ---- last-block final reduction ----
    __threadfence();                       // release partials store
    __shared__ bool last;
    if (tid == 0) {
        unsigned v = atomicAdd(donecnt, 1u);
        last = (v == (unsigned)(2 * RES_BLOCKS - 1));
    }
    __syncthreads();
    if (!last) return;
    __threadfence();                       // acquire all partials

    const volatile float* vp = partials;
    float a2 = 0.0f;
#pragma unroll
    for (int t = 0; t < NPART / NT; t++) a2 += vp[t * NT + tid];
    __shared__ float red[NT];
    red[tid] = a2;
    __syncthreads();
    for (int s2 = NT / 2; s2 > 0; s2 >>= 1) {
        if (tid < s2) red[tid] += red[tid + s2];
        __syncthreads();
    }
    if (tid == 0) out[0] = red[0] * (1.0f / 49152.0f);  // both losses: mean over V*3
}

extern "C" void kernel_launch(void* const* d_in, const int* in_sizes, int n_in,
                              void* d_out, int out_size, void* d_ws, size_t ws_size,
                              hipStream_t stream) {
    const float* pred_v = (const float*)d_in[0];
    const float* trg_v  = (const float*)d_in[1];
    const float* pred_e = (const float*)d_in[2];
    const float* trg_e  = (const float*)d_in[3];
    float* out = (float*)d_out;

    unsigned long long* results = (unsigned long long*)d_ws;  // 2*8*NV u64 = 2 MB
    short* Apack = (short*)(results + 2 * NCHUNK * NV);       // 1 MB
    float* partials = (float*)(Apack + 2 * NTILES * 512);     // 8 KB
    unsigned* donecnt = (unsigned*)(partials + NPART);        // 4 B

    prep_kernel<<<(2 * NTILES * 64) / NT, NT, 0, stream>>>(pred_v, trg_v, Apack, donecnt);

    nn_mfma_kernel<<<dim3(NN_BX, NCHUNK, 2), NT, 0, stream>>>(
        pred_v, trg_v, Apack, results);

    resolve_loss_kernel<<<dim3(RES_BLOCKS, 2), NT, 0, stream>>>(
        pred_v, trg_v, pred_e, trg_e, results, partials, donecnt, out);
}

// Round 8
// 54.058 us; speedup vs baseline: 3.6912x; 3.6912x over previous
//
#include <hip/hip_runtime.h>
#include <hip/hip_bf16.h>

#define NV 16384
#define NT 256
#define NTILES 512                 // 32-point MFMA tiles per mesh
#define WPT 128                    // rtiles scanned per wave
#define RPB 8                      // rtiles per wave per staging round
#define ROUNDS (WPT / RPB)         // 16
#define NPART (2 * NTILES)         // 1024 partials

typedef __attribute__((ext_vector_type(8))) short bf16x8;
typedef __attribute__((ext_vector_type(16))) float f32x16;

__device__ __forceinline__ short bf16bits(float f) {
    __hip_bfloat16 h = __float2bfloat16(f);
    return *reinterpret_cast<short*>(&h);
}
__device__ __forceinline__ float bf16tof(short s) {
    __hip_bfloat16 h = *reinterpret_cast<__hip_bfloat16*>(&s);
    return __bfloat162float(h);
}
__device__ __forceinline__ unsigned sortable(float f) {
    unsigned u = __float_as_uint(f);
    return (u & 0x80000000u) ? ~u : (u | 0x80000000u);
}
__device__ __forceinline__ float min3f(float a, float b, float c) {
    float r;
    asm("v_min3_f32 %0, %1, %2, %3" : "=v"(r) : "v"(a), "v"(b), "v"(c));
    return r;
}
// min over the 16 f32 of one MFMA accumulator (in-lane), 8 ops, depth 3
__device__ __forceinline__ float tree16(const f32x16& c) {
    float t0 = min3f(c[0], c[1], c[2]);
    float t1 = min3f(c[3], c[4], c[5]);
    float t2 = min3f(c[6], c[7], c[8]);
    float t3 = min3f(c[9], c[10], c[11]);
    float t4 = min3f(c[12], c[13], c[14]);
    float s0 = min3f(t0, t1, c[15]);
    float s1 = min3f(t2, t3, t4);
    return fminf(s0, s1);
}

// Fragment packing (K=11 of 16). Metric m(ref,query) = 0.5*||r||^2 - q.r:
//   A(ref) k:   [rh.x rh.y rh.z | rl.x rl.y rl.z | rh.x rh.y || rh.z nh nl | 0..]
//   B(query) k: [-qh.x -qh.y -qh.z | -qh.x -qh.y -qh.z | -ql.x -ql.y || -ql.z 1 1 | 0..]
// vh = bf16(v), vl = bf16(v - f32(vh)), n = 0.5||r||^2 split nh+nl.
// A and B share the (half,elem)->k mapping so any permutation cancels.
__device__ __forceinline__ bf16x8 make_a(float x, float y, float z, int half) {
    short hx = bf16bits(x), hy = bf16bits(y), hz = bf16bits(z);
    short lx = bf16bits(x - bf16tof(hx));
    short ly = bf16bits(y - bf16tof(hy));
    short lz = bf16bits(z - bf16tof(hz));
    float n  = 0.5f * fmaf(z, z, fmaf(y, y, x * x));
    short nh = bf16bits(n);
    short nl = bf16bits(n - bf16tof(nh));
    bf16x8 v;
    v[0] = half ? hz : hx;  v[1] = half ? nh : hy;
    v[2] = half ? nl : hz;  v[3] = half ? (short)0 : lx;
    v[4] = half ? (short)0 : ly;  v[5] = half ? (short)0 : lz;
    v[6] = half ? (short)0 : hx;  v[7] = half ? (short)0 : hy;
    return v;
}
__device__ __forceinline__ bf16x8 make_b(float x, float y, float z, int half) {
    short hx = bf16bits(x), hy = bf16bits(y), hz = bf16bits(z);
    short nhx = bf16bits(-x), nhy = bf16bits(-y), nhz = bf16bits(-z);
    short nlx = bf16bits(bf16tof(hx) - x);
    short nly = bf16bits(bf16tof(hy) - y);
    short nlz = bf16bits(bf16tof(hz) - z);
    const short one = 0x3F80;
    bf16x8 v;
    v[0] = half ? nlz : nhx;  v[1] = half ? one : nhy;
    v[2] = half ? one : nhz;  v[3] = half ? (short)0 : nhx;
    v[4] = half ? (short)0 : nhy;  v[5] = half ? (short)0 : nhz;
    v[6] = half ? (short)0 : nlx;  v[7] = half ? (short)0 : nly;
    return v;
}

// Pack all A (ref-side) fragments once. 1 MB, L2-resident.
__global__ __launch_bounds__(NT) void prep_kernel(
    const float* __restrict__ pred_v, const float* __restrict__ trg_v,
    short* __restrict__ Apack)
{
    int gid = blockIdx.x * NT + threadIdx.x;  // 0..65535
    int d   = gid >> 15;
    int rem = gid & 32767;
    int t   = rem >> 6;
    int l   = rem & 63;
    const float* rpts = d ? trg_v : pred_v;   // refs for dir d
    int p = t * 32 + (l & 31);
    bf16x8 v = make_a(rpts[3 * p + 0], rpts[3 * p + 1], rpts[3 * p + 2], l >> 5);
    *(bf16x8*)(Apack + ((size_t)gid) * 8) = v;
}

// One block = one query tile (32 queries) in one direction. 4 waves each
// scan a disjoint 128-rtile range (full coverage -> argmin is block-local:
// no cross-block results, no atomics, no fences). Then: cross-half shfl
// merge, 4-way LDS merge, exact fp32 rescan of the winning 32-point tile
// (16 pts per lane-half), loss gather, one partial per block.
__global__ __launch_bounds__(NT) void fused_kernel(
    const float* __restrict__ pred_v, const float* __restrict__ trg_v,
    const float* __restrict__ pred_e, const float* __restrict__ trg_e,
    const short* __restrict__ Apack, float* __restrict__ partials)
{
    __shared__ short lds[32 * 512];   // 32 KB: 32 staged tiles
    const int tid = threadIdx.x, lane = tid & 63, w = tid >> 6;
    const int dir = blockIdx.y;
    const int qt  = blockIdx.x;
    const float* qpts = dir ? pred_v : trg_v;
    const float* rpts = dir ? trg_v : pred_v;
    const float* qe_b = dir ? pred_e : trg_e;
    const float* re_b = dir ? trg_e : pred_e;
    const bf16x8* Avec = (const bf16x8*)Apack + (size_t)dir * NTILES * 64;
    bf16x8* ldsv = (bf16x8*)lds;

    const int half = lane >> 5;
    const int qp0 = qt * 32 + (lane & 31);
    const bf16x8 b0 = make_b(qpts[3 * qp0 + 0], qpts[3 * qp0 + 1], qpts[3 * qp0 + 2], half);

    float dmin = 1e30f;
    int bp = 0;
    const f32x16 zc = {};

    for (int r = 0; r < ROUNDS; r++) {
        __syncthreads();
        // stage 32 tiles: 4 chunks of 8 (one per wave's range), coalesced 16 B
#pragma unroll
        for (int it = 0; it < 8; it++) {
            int g = it * NT + tid;            // 0..2047
            int chunk = g >> 9, within = g & 511;
            ldsv[g] = Avec[(chunk * WPT + r * RPB) * 64 + within];
        }
        __syncthreads();
#pragma unroll 4
        for (int i = 0; i < RPB; i++) {
            bf16x8 a = ldsv[(w * RPB + i) * 64 + lane];
            int tile = w * WPT + r * RPB + i;
            f32x16 c = __builtin_amdgcn_mfma_f32_32x32x16_bf16(a, b0, zc, 0, 0, 0);
            float m = tree16(c);
            bool lt = m < dmin;
            dmin = lt ? m : dmin;
            bp = lt ? tile : bp;
        }
    }

    unsigned long long key = ((unsigned long long)sortable(dmin) << 32) | (unsigned)bp;
    { unsigned long long o = __shfl_xor(key, 32); key = (o < key) ? o : key; }

    __syncthreads();   // everyone done reading staged tiles
    unsigned long long* kl = (unsigned long long*)lds;
    if (w > 0 && lane < 32) kl[(w - 1) * 32 + lane] = key;
    __syncthreads();
    if (w != 0) return;

    // wave 0: merge the other 3 waves' keys (lower tile wins ties)
#pragma unroll
    for (int j = 0; j < 3; j++) {
        unsigned long long o = kl[j * 32 + (lane & 31)];
        key = (o < key) ? o : key;
    }

    // exact fp32 rescan of winning tile; halves split 16 pts each
    const int tile = (int)(unsigned)(key & 0xFFFFFFFFULL);
    const float nqx = -qpts[3 * qp0 + 0];
    const float nqy = -qpts[3 * qp0 + 1];
    const float nqz = -qpts[3 * qp0 + 2];
    float dm = 1e30f;
    int jm = tile * 32;
    const int p0 = tile * 32 + half * 16;
#pragma unroll 4
    for (int pt = 0; pt < 16; pt++) {
        int j = p0 + pt;
        float x = rpts[3 * j + 0], y = rpts[3 * j + 1], z = rpts[3 * j + 2];
        float rw = 0.5f * fmaf(z, z, fmaf(y, y, x * x));
        float s = fmaf(nqx, x, rw);
        s = fmaf(nqy, y, s);
        s = fmaf(nqz, z, s);
        bool lt = s < dm;   // strict: earliest j within half
        dm = lt ? s : dm;
        jm = lt ? j : jm;
    }
    unsigned long long kk = ((unsigned long long)sortable(dm) << 32) | (unsigned)jm;
    { unsigned long long o = __shfl_xor(kk, 32); kk = (o < kk) ? o : kk; }  // lower j wins ties

    float contrib = 0.0f;
    if (lane < 32) {
        int j = (int)(unsigned)(kk & 0xFFFFFFFFULL);
        float dx = qe_b[3 * qp0 + 0] - re_b[3 * j + 0];
        float dy = qe_b[3 * qp0 + 1] - re_b[3 * j + 1];
        float dz = qe_b[3 * qp0 + 2] - re_b[3 * j + 2];
        contrib = fmaf(dx, dx, fmaf(dy, dy, dz * dz));
    }
#pragma unroll
    for (int off = 32; off > 0; off >>= 1) contrib += __shfl_xor(contrib, off);
    if (lane == 0) partials[dir * NTILES + qt] = contrib;
}

__global__ __launch_bounds__(NT) void final_kernel(
    const float* __restrict__ partials, float* __restrict__ out)
{
    const int tid = threadIdx.x;
    float acc = (partials[tid] + partials[tid + 256])
              + (partials[tid + 512] + partials[tid + 768]);
    __shared__ float red[NT];
    red[tid] = acc;
    __syncthreads();
    for (int s = NT / 2; s > 0; s >>= 1) {
        if (tid < s) red[tid] += red[tid + s];
        __syncthreads();
    }
    if (tid == 0) out[0] = red[0] * (1.0f / 49152.0f);  // both losses: mean over V*3
}

extern "C" void kernel_launch(void* const* d_in, const int* in_sizes, int n_in,
                              void* d_out, int out_size, void* d_ws, size_t ws_size,
                              hipStream_t stream) {
    const float* pred_v = (const float*)d_in[0];
    const float* trg_v  = (const float*)d_in[1];
    const float* pred_e = (const float*)d_in[2];
    const float* trg_e  = (const float*)d_in[3];
    float* out = (float*)d_out;

    short* Apack = (short*)d_ws;                          // 2*512*512 shorts = 1 MB
    float* partials = (float*)(Apack + 2 * NTILES * 512); // 1024 floats

    prep_kernel<<<(2 * NTILES * 64) / NT, NT, 0, stream>>>(pred_v, trg_v, Apack);

    fused_kernel<<<dim3(NTILES, 2), NT, 0, stream>>>(
        pred_v, trg_v, pred_e, trg_e, Apack, partials);

    final_kernel<<<1, NT, 0, stream>>>(partials, out);
}

// Round 9
// 45.837 us; speedup vs baseline: 4.3533x; 1.1794x over previous
//
#include <hip/hip_runtime.h>
#include <hip/hip_bf16.h>

#define NV 16384
#define NT 256
#define NTILES 512                  // 32-point MFMA tiles per mesh
#define NCH 8                       // ref chunks per direction
#define CHT (NTILES / NCH)          // 64 rtiles per chunk
#define QPW 2                       // query tiles per wave
#define NN_BX (NTILES / (4 * QPW))  // 64 blocks in x (4 waves/block)
#define RES_QPW 4                   // queries per wave (resolve)
#define RES_QPB 16                  // per block
#define RES_BLOCKS (NV / RES_QPB)   // 1024 per direction
#define NPART (2 * RES_BLOCKS)      // 2048 partials

typedef __attribute__((ext_vector_type(8))) short bf16x8;
typedef __attribute__((ext_vector_type(16))) float f32x16;

__device__ __forceinline__ short bf16bits(float f) {
    __hip_bfloat16 h = __float2bfloat16(f);
    return *reinterpret_cast<short*>(&h);
}
__device__ __forceinline__ float bf16tof(short s) {
    __hip_bfloat16 h = *reinterpret_cast<__hip_bfloat16*>(&s);
    return __bfloat162float(h);
}
__device__ __forceinline__ unsigned sortable(float f) {
    unsigned u = __float_as_uint(f);
    return (u & 0x80000000u) ? ~u : (u | 0x80000000u);
}
__device__ __forceinline__ float min3f(float a, float b, float c) {
    float r;
    asm("v_min3_f32 %0, %1, %2, %3" : "=v"(r) : "v"(a), "v"(b), "v"(c));
    return r;
}
// min over the 16 f32 of one MFMA accumulator (in-lane), 8 ops, depth 3
__device__ __forceinline__ float tree16(const f32x16& c) {
    float t0 = min3f(c[0], c[1], c[2]);
    float t1 = min3f(c[3], c[4], c[5]);
    float t2 = min3f(c[6], c[7], c[8]);
    float t3 = min3f(c[9], c[10], c[11]);
    float t4 = min3f(c[12], c[13], c[14]);
    float s0 = min3f(t0, t1, c[15]);
    float s1 = min3f(t2, t3, t4);
    return fminf(s0, s1);
}

// MFMA with VGPR-forced D and C (inline asm). The builtin path put the
// accumulator in AGPRs -> 16 v_accvgpr_write (zero C) + 16 v_accvgpr_read
// (tree16) per MFMA = the ~6x VALU inflation measured in R8. "=&v" keeps D
// off A/B/C; zc (16 VGPRs of zeros, init once) survives every call.
__device__ __forceinline__ f32x16 mfma_tile(bf16x8 a, bf16x8 b, f32x16 zc) {
    f32x16 d;
    asm("v_mfma_f32_32x32x16_bf16 %0, %1, %2, %3"
        : "=&v"(d) : "v"(a), "v"(b), "v"(zc));
    return d;
}

// Fragment packing (K=11 of 16). Metric m(ref,query) = 0.5*||r||^2 - q.r:
//   A(ref) k:   [rh.x rh.y rh.z | rl.x rl.y rl.z | rh.x rh.y || rh.z nh nl | 0..]
//   B(query) k: [-qh.x -qh.y -qh.z | -qh.x -qh.y -qh.z | -ql.x -ql.y || -ql.z 1 1 | 0..]
// vh = bf16(v), vl = bf16(v - f32(vh)), n = 0.5||r||^2 split nh+nl.
// A and B share the (half,elem)->k mapping so any permutation cancels.
__device__ __forceinline__ bf16x8 make_a(float x, float y, float z, int half) {
    short hx = bf16bits(x), hy = bf16bits(y), hz = bf16bits(z);
    short lx = bf16bits(x - bf16tof(hx));
    short ly = bf16bits(y - bf16tof(hy));
    short lz = bf16bits(z - bf16tof(hz));
    float n  = 0.5f * fmaf(z, z, fmaf(y, y, x * x));
    short nh = bf16bits(n);
    short nl = bf16bits(n - bf16tof(nh));
    bf16x8 v;
    v[0] = half ? hz : hx;  v[1] = half ? nh : hy;
    v[2] = half ? nl : hz;  v[3] = half ? (short)0 : lx;
    v[4] = half ? (short)0 : ly;  v[5] = half ? (short)0 : lz;
    v[6] = half ? (short)0 : hx;  v[7] = half ? (short)0 : hy;
    return v;
}
__device__ __forceinline__ bf16x8 make_b(float x, float y, float z, int half) {
    short hx = bf16bits(x), hy = bf16bits(y), hz = bf16bits(z);
    short nhx = bf16bits(-x), nhy = bf16bits(-y), nhz = bf16bits(-z);
    short nlx = bf16bits(bf16tof(hx) - x);
    short nly = bf16bits(bf16tof(hy) - y);
    short nlz = bf16bits(bf16tof(hz) - z);
    const short one = 0x3F80;
    bf16x8 v;
    v[0] = half ? nlz : nhx;  v[1] = half ? one : nhy;
    v[2] = half ? one : nhz;  v[3] = half ? (short)0 : nhx;
    v[4] = half ? (short)0 : nhy;  v[5] = half ? (short)0 : nhz;
    v[6] = half ? (short)0 : nlx;  v[7] = half ? (short)0 : nly;
    return v;
}

// Pack all A (ref-side) fragments once. 1 MB, L2-resident.
__global__ __launch_bounds__(NT) void prep_kernel(
    const float* __restrict__ pred_v, const float* __restrict__ trg_v,
    short* __restrict__ Apack)
{
    int gid = blockIdx.x * NT + threadIdx.x;  // 0..65535
    int d   = gid >> 15;
    int rem = gid & 32767;
    int t   = rem >> 6;
    int l   = rem & 63;
    const float* rpts = d ? trg_v : pred_v;   // refs for dir d
    int p = t * 32 + (l & 31);
    bf16x8 v = make_a(rpts[3 * p + 0], rpts[3 * p + 1], rpts[3 * p + 2], l >> 5);
    *(bf16x8*)(Apack + ((size_t)gid) * 8) = v;
}

// Pass 1: MFMA all-pairs min, no LDS, no barriers. Each wave: 2 qtiles vs
// one 64-rtile chunk; A fragments streamed straight from L2 (16 B/lane,
// coalesced); the block's 4 waves scan the SAME chunk in lockstep so L1
// serves ~4x. Per rtile: 2 asm-MFMAs + min3 trees; track (dmin, tile);
// cross-half shfl merge; per-chunk key store (no atomics).
__global__ __launch_bounds__(NT) void nn_mfma_kernel(
    const float* __restrict__ pred_v, const float* __restrict__ trg_v,
    const short* __restrict__ Apack, unsigned long long* __restrict__ results)
{
    const int tid = threadIdx.x, lane = tid & 63, w = tid >> 6;
    const int dir = blockIdx.z, ch = blockIdx.y;
    const float* qpts = dir ? pred_v : trg_v;
    const int qt0 = (blockIdx.x * 4 + w) * QPW;
    const int half = lane >> 5;
    const bf16x8* Avec = (const bf16x8*)Apack + (size_t)dir * NTILES * 64;

    const int qp0 = qt0 * 32 + (lane & 31);
    bf16x8 b0 = make_b(qpts[3 * qp0 + 0], qpts[3 * qp0 + 1], qpts[3 * qp0 + 2], half);
    bf16x8 b1 = make_b(qpts[3 * (qp0 + 32) + 0], qpts[3 * (qp0 + 32) + 1],
                       qpts[3 * (qp0 + 32) + 2], half);

    f32x16 zc = {};   // 16 VGPRs of zeros, init once, reused by every MFMA
    float dmin0 = 1e30f, dmin1 = 1e30f;
    int bp0 = 0, bp1 = 0;

    const bf16x8* ap = Avec + (size_t)(ch * CHT) * 64 + lane;
#pragma unroll 2
    for (int t = 0; t < CHT; t++) {
        bf16x8 a = ap[t * 64];
        int tile = ch * CHT + t;
        f32x16 d0 = mfma_tile(a, b0, zc);
        float m0 = tree16(d0);
        bool l0 = m0 < dmin0;
        dmin0 = l0 ? m0 : dmin0;
        bp0 = l0 ? tile : bp0;
        f32x16 d1 = mfma_tile(a, b1, zc);
        float m1 = tree16(d1);
        bool l1 = m1 < dmin1;
        dmin1 = l1 ? m1 : dmin1;
        bp1 = l1 ? tile : bp1;
    }

    unsigned long long k0 = ((unsigned long long)sortable(dmin0) << 32) | (unsigned)bp0;
    unsigned long long k1 = ((unsigned long long)sortable(dmin1) << 32) | (unsigned)bp1;
    { unsigned long long o = __shfl_xor(k0, 32); k0 = (o < k0) ? o : k0; }
    { unsigned long long o = __shfl_xor(k1, 32); k1 = (o < k1) ? o : k1; }
    if (lane < 32) {
        size_t base = ((size_t)dir * NCH + ch) * NV;
        results[base + qt0 * 32 + lane] = k0;
        results[base + (qt0 + 1) * 32 + lane] = k1;
    }
}

// Pass 2 + loss (fence-free R6 form). Per query: min over 8 chunk keys
// (lowest tile wins ties), exact fp32 rescan of the winning 32-point tile
// (lanes 32-63 duplicate; packed-u64 lane-min -> first-occurrence argmin),
// lane 0 accumulates MSE; deterministic block reduce to partials.
__global__ __launch_bounds__(NT) void resolve_loss_kernel(
    const float* __restrict__ pred_v, const float* __restrict__ trg_v,
    const float* __restrict__ pred_e, const float* __restrict__ trg_e,
    const unsigned long long* __restrict__ results, float* __restrict__ partials)
{
    const int dir = blockIdx.y;
    const float* qpts = dir ? pred_v : trg_v;
    const float* rpts = dir ? trg_v : pred_v;
    const float* qe_b = dir ? pred_e : trg_e;
    const float* re_b = dir ? trg_e : pred_e;

    const int tid = threadIdx.x, lane = tid & 63, wv = tid >> 6;
    float acc = 0.0f;

    for (int qq = 0; qq < RES_QPW; qq++) {
        const int q = blockIdx.x * RES_QPB + wv * RES_QPW + qq;

        unsigned long long key = 0xFFFFFFFFFFFFFFFFULL;
        if (lane < NCH)
            key = results[((size_t)dir * NCH + lane) * NV + q];
        unsigned long long o;
        o = __shfl_xor(key, 4); key = (o < key) ? o : key;
        o = __shfl_xor(key, 2); key = (o < key) ? o : key;
        o = __shfl_xor(key, 1); key = (o < key) ? o : key;
        key = __shfl(key, 0);
        const int tile = (int)(unsigned)(key & 0xFFFFFFFFULL);
        const int i = tile * 32 + (lane & 31);   // lanes 32-63 duplicate

        float nqx = -qpts[3 * q + 0], nqy = -qpts[3 * q + 1], nqz = -qpts[3 * q + 2];
        float x = rpts[3 * i + 0], y = rpts[3 * i + 1], z = rpts[3 * i + 2];
        float rw = 0.5f * fmaf(z, z, fmaf(y, y, x * x));
        float s = fmaf(nqx, x, rw);
        s = fmaf(nqy, y, s);
        s = fmaf(nqz, z, s);

        unsigned long long kk = ((unsigned long long)sortable(s) << 32) | (unsigned)i;
#pragma unroll
        for (int off = 32; off > 0; off >>= 1) {
            unsigned long long t = __shfl_xor(kk, off);
            kk = (t < kk) ? t : kk;
        }
        if (lane == 0) {
            int j = (int)(unsigned)(kk & 0xFFFFFFFFULL);
            float dx = qe_b[3 * q + 0] - re_b[3 * j + 0];
            float dy = qe_b[3 * q + 1] - re_b[3 * j + 1];
            float dz = qe_b[3 * q + 2] - re_b[3 * j + 2];
            acc += fmaf(dx, dx, fmaf(dy, dy, dz * dz));
        }
    }

    __shared__ float wsum[4];
    if (lane == 0) wsum[wv] = acc;
    __syncthreads();
    if (tid == 0)
        partials[dir * RES_BLOCKS + blockIdx.x] =
            (wsum[0] + wsum[1]) + (wsum[2] + wsum[3]);
}

__global__ __launch_bounds__(NT) void final_kernel(
    const float* __restrict__ partials, float* __restrict__ out)
{
    const int tid = threadIdx.x;
    float acc = 0.0f;
#pragma unroll
    for (int t = 0; t < NPART / NT; t++) acc += partials[t * NT + tid];
    __shared__ float red[NT];
    red[tid] = acc;
    __syncthreads();
    for (int s = NT / 2; s > 0; s >>= 1) {
        if (tid < s) red[tid] += red[tid + s];
        __syncthreads();
    }
    if (tid == 0) out[0] = red[0] * (1.0f / 49152.0f);  // both losses: mean over V*3
}

extern "C" void kernel_launch(void* const* d_in, const int* in_sizes, int n_in,
                              void* d_out, int out_size, void* d_ws, size_t ws_size,
                              hipStream_t stream) {
    const float* pred_v = (const float*)d_in[0];
    const float* trg_v  = (const float*)d_in[1];
    const float* pred_e = (const float*)d_in[2];
    const float* trg_e  = (const float*)d_in[3];
    float* out = (float*)d_out;

    unsigned long long* results = (unsigned long long*)d_ws;  // 2*8*NV u64 = 2 MB
    short* Apack = (short*)(results + 2 * NCH * NV);          // 1 MB
    float* partials = (float*)(Apack + 2 * NTILES * 512);     // 8 KB

    prep_kernel<<<(2 * NTILES * 64) / NT, NT, 0, stream>>>(pred_v, trg_v, Apack);

    nn_mfma_kernel<<<dim3(NN_BX, NCH, 2), NT, 0, stream>>>(
        pred_v, trg_v, Apack, results);

    resolve_loss_kernel<<<dim3(RES_BLOCKS, 2), NT, 0, stream>>>(
        pred_v, trg_v, pred_e, trg_e, results, partials);

    final_kernel<<<1, NT, 0, stream>>>(partials, out);
}